// Round 11
// baseline (57.232 us; speedup 1.0000x reference)
//
#include <hip/hip_runtime.h>

// Steered 3x3 conv as per-pixel GEMM (K=256 = 64ch x 4 feats) via bf16 MFMA.
// v11: full-width tile, 1 block/CU, weights-in-LDS, clean depth-1 pipeline.
//  - TILE = 8 rows x 128 cols (whole width): staging DMA is fully contiguous
//    (each global_load_lds = 1KB = 2 complete image rows). Fixes the 160B-
//    burst HBM inefficiency of r4-r8's 40-col tiles.
//  - Weights live in LDS (staged once at prologue): the K-loop's only VMEM
//    is staging, so the phase-head vmcnt(0) waits exactly one chunk whose DMA
//    was issued a full compute-phase earlier. Fixes r8's weight-load vmcnt
//    poisoning and r6's __syncthreads vmcnt(0)-drain (both collapsed depth).
//  - Boundary: OOB halo slots are never DMA'd and pre-zeroed once; w-edges
//    via float masks. No per-chunk fix passes.
//  - LDS = 32KB weights + 2 x 48KB x-buffers = 128KB; 1024-thr block; grid
//    256 = 1 block/CU, all co-resident. launch_bounds(1024,4) => <=128 regs.
// B-frag: lane l -> col = l&31 (pixel), k = 16*kcg + 8*(l>>5) + r (verified r2)
// C/D:    col = lane&31, row(o) = (r&3) + 8*(r>>2) + 4*(lane>>5)  (verified r2)

typedef __bf16 bf16x8 __attribute__((ext_vector_type(8)));
typedef float  f32x16 __attribute__((ext_vector_type(16)));
typedef unsigned int u32;
typedef const __attribute__((address_space(1))) u32* gp_t;
typedef __attribute__((address_space(3))) u32* lp_t;

#define HH 128
#define WW 128
#define HW 16384
#define CHIMG 65536          // bytes per (n,ch) plane

// Weights f32[o][k] -> bf16 grouped per MFMA A-fragment:
// wb[((kcg*2+hx)*64 + o)*8 + r] = bf16(wt[o][kcg*16 + hx*8 + r])
__global__ void wt_repack(const float* __restrict__ wt,
                          unsigned short* __restrict__ wb) {
    int i = blockIdx.x * 256 + threadIdx.x;   // i = o*256 + k
    int o = i >> 8, k = i & 255;
    union { float f; u32 u; } v; v.f = wt[i];
    unsigned short b = (unsigned short)((v.u + 0x7FFF + ((v.u >> 16) & 1)) >> 16);
    int kcg = k >> 4, hxx = (k >> 3) & 1, r = k & 7;
    wb[((kcg * 2 + hxx) * 64 + o) * 8 + r] = b;
}

__global__ __launch_bounds__(1024, 4) void steered_conv_mfma(
    const float* __restrict__ x, const float* __restrict__ theta,
    const unsigned short* __restrict__ wb, const float* __restrict__ bias,
    float* __restrict__ out)
{
    __shared__ unsigned short wlds[16384];                           // 32 KB
    __shared__ __attribute__((aligned(16))) float xb[2][8][12][128]; // 96 KB

    const int tid  = threadIdx.x;
    const int W    = tid >> 6, lane = tid & 63;
    const int pc   = lane & 31, hx = lane >> 5;
    const int p0   = (W >> 2) * 2;   // wave's first pixel row within tile
    const int w    = (W & 3) * 32 + pc;

    // XCD swizzle: 256 blocks, 32/XCD = 2 whole images per XCD
    const int bb  = blockIdx.x;
    const int swz = (bb & 7) * 32 + (bb >> 3);
    const int n   = swz >> 4;
    const int h0  = (swz & 15) * 8;

    const char* xn = (const char*)x + (size_t)n * 64 * CHIMG;

    // ---- prologue: weights -> LDS (2 DMA/thread-slice) ----
    {
        const char* s = (const char*)wb + tid * 16;
        char* d = (char*)wlds + W * 1024;                 // uniform per wave
        __builtin_amdgcn_global_load_lds((gp_t)s, (lp_t)d, 16, 0, 0);
        __builtin_amdgcn_global_load_lds((gp_t)(s + 16384), (lp_t)(d + 16384), 16, 0, 0);
    }

    // per-wave staging assignment: 3 (ch, row-pair) units; 8ch x 6 pairs = 48
    const int i0  = W * 3;
    const int ch0 = i0 / 6,       pr0 = i0 - ch0 * 6;
    const int ch1 = (i0+1) / 6,   pr1 = (i0+1) - ch1 * 6;
    const int ch2 = (i0+2) / 6,   pr2 = (i0+2) - ch2 * 6;
    char* const xldsb = (char*)&xb[0][0][0][0];

    auto stage = [&](int t) {   // rows h0-2..h0+9 in slots 0..11, 2 rows/DMA
        const char* xc = xn + (size_t)(t * 8) * CHIMG + lane * 16;
        char* db = xldsb + (t & 1) * 49152;
        if (!((h0 == 0 && pr0 == 0) || (h0 == 120 && pr0 == 5)))
            __builtin_amdgcn_global_load_lds(
                (gp_t)(xc + ch0 * CHIMG + (h0 - 2 + 2 * pr0) * 512),
                (lp_t)(db + ch0 * 6144 + pr0 * 1024), 16, 0, 0);
        if (!((h0 == 0 && pr1 == 0) || (h0 == 120 && pr1 == 5)))
            __builtin_amdgcn_global_load_lds(
                (gp_t)(xc + ch1 * CHIMG + (h0 - 2 + 2 * pr1) * 512),
                (lp_t)(db + ch1 * 6144 + pr1 * 1024), 16, 0, 0);
        if (!((h0 == 0 && pr2 == 0) || (h0 == 120 && pr2 == 5)))
            __builtin_amdgcn_global_load_lds(
                (gp_t)(xc + ch2 * CHIMG + (h0 - 2 + 2 * pr2) * 512),
                (lp_t)(db + ch2 * 6144 + pr2 * 1024), 16, 0, 0);
    };
    stage(0);

    // theta + harmonics for the wave's two pixel rows
    float s1a, c1a, s1b, c1b;
    __sincosf(6.2831853071795864769f * theta[(n*HH + h0+p0)*WW + w], &s1a, &c1a);
    __sincosf(6.2831853071795864769f * theta[(n*HH + h0+p0+1)*WW + w], &s1b, &c1b);
    const float c2a = 2.f*c1a*c1a - 1.f, s2a = 2.f*s1a*c1a;
    const float c2b = 2.f*c1b*c1b - 1.f, s2b = 2.f*s1b*c1b;

    // pre-zero the never-DMA'd OOB halo slots (both buffers)
    if (h0 == 0 || h0 == 120) {
        const int sb = (h0 == 0) ? 0 : 10;
        for (int i = tid; i < 4096; i += 1024) {
            const int b   = i >> 11;
            const int ch  = (i >> 8) & 7;
            const int rr  = (i >> 7) & 1;
            const int col = i & 127;
            xb[b][ch][sb + rr][col] = 0.f;
        }
    }
    __syncthreads();   // weights + chunk0 landed; pre-zero visible

    // w-edge masks + clamped tap columns
    const float fL = (w > 0) ? 1.f : 0.f;
    const float fR = (w < WW - 1) ? 1.f : 0.f;
    const int  wLo = (w > 0) ? w - 1 : 0;
    const int  wRo = (w < WW - 1) ? w + 1 : WW - 1;

    // per-lane tap base pointers; all per-phase offsets are immediates
    const float* pL = &xb[0][0][0][0] + hx * 3072 + (p0 + 1) * 128 + wLo;
    const float* pC = &xb[0][0][0][0] + hx * 3072 + (p0 + 1) * 128 + w;
    const float* pR = &xb[0][0][0][0] + hx * 3072 + (p0 + 1) * 128 + wRo;

    f32x16 acc00, acc01, acc10, acc11;
    #pragma unroll
    for (int r = 0; r < 16; ++r) { acc00[r]=0.f; acc01[r]=0.f; acc10[r]=0.f; acc11[r]=0.f; }

    const float RS  = 0.35355339059327373f;   // sqrt(2)/4
    const float HMR = 0.14644660940672627f;   // 0.5 - RS

    #pragma unroll
    for (int c = 0; c < 8; ++c) {
        asm volatile("s_waitcnt vmcnt(0)" ::: "memory");  // chunk c landed
        __builtin_amdgcn_s_barrier();
        __builtin_amdgcn_sched_barrier(0);
        if (c < 7) stage(c + 1);          // overlaps compute(c); other buffer
        __builtin_amdgcn_sched_barrier(0);

        #pragma unroll
        for (int kc = 0; kc < 2; ++kc) {
            const int kcg = c * 2 + kc;
            const bf16x8 A0 = *(const bf16x8*)&wlds[((kcg*2 + hx)*64 + pc) * 8];
            const bf16x8 A1 = *(const bf16x8*)&wlds[((kcg*2 + hx)*64 + 32 + pc) * 8];
            bf16x8 b0, b1;
            #pragma unroll
            for (int cs = 0; cs < 2; ++cs) {
                const int off = (c & 1) * 12288 + (kc * 4 + cs) * 1536;
                float S[4], D[4], C[4];
                #pragma unroll
                for (int r = 0; r < 4; ++r) {
                    const float tL = pL[off + r * 128];
                    const float tC = pC[off + r * 128];
                    const float tR = pR[off + r * 128];
                    const float a = fL * tL, cc = fR * tR;
                    S[r] = a + tC + cc;
                    D[r] = cc - a;
                    C[r] = tC;
                }
                {   // pixel row p0 (tap rows 0,1,2)
                    const float T  = S[1] - C[1];
                    const float F1 = RS * (S[0] + S[2] + T);
                    const float B2 = RS * (D[0] + D[2]) + 0.5f * D[1];
                    const float B3 = RS * (S[2] - S[0]) + HMR * (C[2] - C[0]);
                    const float B4 = 0.5f * (T - (C[0] + C[2]));
                    const float B5 = 0.5f * (D[2] - D[0]);
                    b0[cs*4+0] = (__bf16)C[1];
                    b0[cs*4+1] = (__bf16)F1;
                    b0[cs*4+2] = (__bf16)(c1a * B2 + s1a * B3);
                    b0[cs*4+3] = (__bf16)(c2a * B4 + s2a * B5);
                }
                {   // pixel row p0+1 (tap rows 1,2,3)
                    const float T  = S[2] - C[2];
                    const float F1 = RS * (S[1] + S[3] + T);
                    const float B2 = RS * (D[1] + D[3]) + 0.5f * D[2];
                    const float B3 = RS * (S[3] - S[1]) + HMR * (C[3] - C[1]);
                    const float B4 = 0.5f * (T - (C[1] + C[3]));
                    const float B5 = 0.5f * (D[3] - D[1]);
                    b1[cs*4+0] = (__bf16)C[2];
                    b1[cs*4+1] = (__bf16)F1;
                    b1[cs*4+2] = (__bf16)(c1b * B2 + s1b * B3);
                    b1[cs*4+3] = (__bf16)(c2b * B4 + s2b * B5);
                }
            }
            __builtin_amdgcn_s_setprio(1);
            acc00 = __builtin_amdgcn_mfma_f32_32x32x16_bf16(A0, b0, acc00, 0, 0, 0);
            acc01 = __builtin_amdgcn_mfma_f32_32x32x16_bf16(A1, b0, acc01, 0, 0, 0);
            acc10 = __builtin_amdgcn_mfma_f32_32x32x16_bf16(A0, b1, acc10, 0, 0, 0);
            acc11 = __builtin_amdgcn_mfma_f32_32x32x16_bf16(A1, b1, acc11, 0, 0, 0);
            __builtin_amdgcn_s_setprio(0);
        }
    }

    const size_t hw = (size_t)HW;
    float* op = out + (size_t)n * 64 * hw + (size_t)(h0 + p0) * WW + w;
    #pragma unroll
    for (int r = 0; r < 16; ++r) {
        const int o = (r & 3) + 8 * (r >> 2) + 4 * hx;
        const float bo = bias[o], bo2 = bias[o + 32];
        op[(size_t)o * hw]             = acc00[r] + bo;
        op[(size_t)(o + 32) * hw]      = acc01[r] + bo2;
        op[(size_t)o * hw + WW]        = acc10[r] + bo;
        op[(size_t)(o + 32) * hw + WW] = acc11[r] + bo2;
    }
}

extern "C" void kernel_launch(void* const* d_in, const int* in_sizes, int n_in,
                              void* d_out, int out_size, void* d_ws, size_t ws_size,
                              hipStream_t stream) {
    const float* x     = (const float*)d_in[0];
    const float* theta = (const float*)d_in[1];
    const float* wt    = (const float*)d_in[2];
    const float* bias  = (const float*)d_in[3];
    float* out = (float*)d_out;
    unsigned short* wb = (unsigned short*)d_ws;   // 32 KB bf16 weights (repacked)

    wt_repack<<<64, 256, 0, stream>>>(wt, wb);

    steered_conv_mfma<<<256, 1024, 0, stream>>>(x, theta, wb, bias, out);
}

// Round 12
// 41.843 us; speedup vs baseline: 1.3678x; 1.3678x over previous
//
#include <hip/hip_runtime.h>

// Steered 3x3 conv as per-pixel GEMM (K=256 = 64ch x 4 feats) via bf16 MFMA.
// v12 = r8 skeleton + TRUE depth-2 pipeline:
//  r8's flaw (found via r11 analysis): per-phase weight loads sit BEHIND the
//  staged x-prefetch in the in-order vmcnt queue, so the compiler's wait to
//  consume weights mid-phase force-retired the next chunk's DMA (depth ~1).
//  Fix: prefetch w(c+1) into REGISTERS right after phase-c's barrier, BEFORE
//  stage(c+2). Steady-state queue at phase head = [s(c):4, w(c):4, s(c+1):4]
//  -> one vmcnt(4) retires s(c)+w(c) together; weight use mid-phase is a
//  non-blocking wait; prefetch keeps 2 full phases of cover.
//  Cost: 2 live weight sets = +32 VGPR -> launch_bounds(256,3) (cap 170,
//  no spill; r5/r11 showed spill = instant 2x loss). 12 waves/CU vs r8's 8.
// B-frag: lane l -> col = l&31 (pixel), k = 16*kc + 8*(l>>5) + r  (verified r2)
// C/D:    col = lane&31, row(o) = (r&3) + 8*(r>>2) + 4*(lane>>5)  (verified r2)

typedef __bf16 bf16x8 __attribute__((ext_vector_type(8)));
typedef float  f32x16 __attribute__((ext_vector_type(16)));
typedef float  f32x4  __attribute__((ext_vector_type(4)));
typedef unsigned int u32;
typedef const __attribute__((address_space(1))) u32* gp_t;
typedef __attribute__((address_space(3))) u32* lp_t;

#define HH 128
#define WW 128
#define CHCH 8              // channels per chunk
#define NCHUNK 8
#define NBUF 3              // triple buffer: prefetch depth 2
#define RROWS 10
#define RCOLS 40
#define CHF 400             // floats per channel slot
#define CHIMG 65536         // bytes per (n,ch) plane

// Weights f32[o][k] -> bf16 grouped per MFMA A-fragment (coalesced loads):
// wb[((kcg*2+hx)*64 + o)*8 + r] = bf16(wt[o][kcg*16 + hx*8 + r])
__global__ void wt_repack(const float* __restrict__ wt,
                          unsigned short* __restrict__ wb) {
    int i = blockIdx.x * 256 + threadIdx.x;   // i = o*256 + k
    int o = i >> 8, k = i & 255;
    union { float f; u32 u; } v; v.f = wt[i];
    unsigned short b = (unsigned short)((v.u + 0x7FFF + ((v.u >> 16) & 1)) >> 16);
    int kcg = k >> 4, hxx = (k >> 3) & 1, r = k & 7;
    wb[((kcg * 2 + hxx) * 64 + o) * 8 + r] = b;
}

__global__ __launch_bounds__(256, 3) void steered_conv_mfma(
    const float* __restrict__ x, const float* __restrict__ theta,
    const unsigned short* __restrict__ wb, const float* __restrict__ bias,
    float* __restrict__ out)
{
    __shared__ __attribute__((aligned(16))) float lds[NBUF][CHCH][CHF]; // 38400 B

    const int tid = threadIdx.x;
    const int wid = tid >> 6, lane = tid & 63;
    const int pc = lane & 31, hx = lane >> 5;

    // bijective XCD swizzle: 1024 blocks, 128/XCD = 2 whole images
    const int bb = blockIdx.x;
    const int swz = (bb & 7) * 128 + (bb >> 3);
    const int n = swz >> 6;
    const int ty = (swz >> 2) & 15, tx = swz & 3;
    const int h0 = ty * 8, w0 = tx * 32;
    const int p0 = wid * 2;

    // ---- per-lane DMA constants; skip-masks cover OOB halo rows/cols ----
    const int oA = lane * 16;
    const int rA = oA / 160;
    const int cA = oA - rA * 160;
    int ghA = h0 - 1 + rA; ghA = ghA < 0 ? 0 : (ghA > 127 ? 127 : ghA);
    int srcA = ghA * 512 + w0 * 4 - 16 + cA;
    srcA = srcA < 0 ? 0 : srcA;
    const bool skA = (w0 == 0 && cA < 16) || (w0 == 96 && cA >= 144)
                   || (h0 == 0 && rA == 0);

    const int oB = 1024 + lane * 16;
    const int rB = oB / 160;
    const int cB = oB - rB * 160;
    int ghB = h0 - 1 + rB; ghB = ghB < 0 ? 0 : (ghB > 127 ? 127 : ghB);
    int srcB = ghB * 512 + w0 * 4 - 16 + cB;
    srcB = srcB < 0 ? 0 : (srcB > CHIMG - 16 ? CHIMG - 16 : srcB);
    const bool skB = (lane >= 36) || (w0 == 0 && cB < 16) || (w0 == 96 && cB >= 144)
                   || (h0 == 120 && rB == 9);

    const char* xn = (const char*)x + (size_t)n * 64 * CHIMG;

    // ---- theta + harmonics (VMEM retires before the pipeline starts) ----
    float s1a, c1a, s1b, c1b;
    __sincosf(6.2831853071795864769f * theta[(n*HH + h0+p0)*WW + w0+pc], &s1a, &c1a);
    __sincosf(6.2831853071795864769f * theta[(n*HH + h0+p0+1)*WW + w0+pc], &s1b, &c1b);
    const float c2a = 2.f*c1a*c1a - 1.f, s2a = 2.f*s1a*c1a;
    const float c2b = 2.f*c1b*c1b - 1.f, s2b = 2.f*s1b*c1b;

    // ---- one-time pre-zero for boundary tiles (skipped DMA slots read 0) ----
    if ((h0 == 0) | (h0 == 120) | (w0 == 0) | (w0 == 96)) {
        f32x4* z = (f32x4*)&lds[0][0][0];
        for (int i = tid; i < NBUF * CHCH * CHF / 4; i += 256)
            z[i] = f32x4{0.f, 0.f, 0.f, 0.f};
    }
    __syncthreads();

    auto stage = [&](int t) {
        const char* xc = xn + (size_t)(t * CHCH) * CHIMG;
        #pragma unroll
        for (int j = 0; j < 2; ++j) {
            const int ch = wid * 2 + j;
            const char* s = xc + ch * CHIMG;
            char* d = (char*)&lds[t % NBUF][ch][0];
            if (!skA) __builtin_amdgcn_global_load_lds((gp_t)(s + srcA), (lp_t)d, 16, 0, 0);
            if (!skB) __builtin_amdgcn_global_load_lds((gp_t)(s + srcB), (lp_t)(d + 1024), 16, 0, 0);
        }
    };

    const unsigned short* wbl = wb + (hx * 64 + pc) * 8;
    bf16x8 wE0, wE1, wE2, wE3, wO0, wO1, wO2, wO3;   // even/odd phase sets

    // prologue: stage(0); w(0); stage(1)  -> queue [s0:4, w0:4, s1:4]
    stage(0);
    {
        const unsigned short* wr = wbl;              // phase 0
        wE0 = *(const bf16x8*)(wr);
        wE1 = *(const bf16x8*)(wr + 256);
        wE2 = *(const bf16x8*)(wr + 1024);
        wE3 = *(const bf16x8*)(wr + 1280);
    }
    stage(1);

    f32x16 acc00, acc01, acc10, acc11;
    #pragma unroll
    for (int r = 0; r < 16; ++r) { acc00[r]=0.f; acc01[r]=0.f; acc10[r]=0.f; acc11[r]=0.f; }

    const float RS  = 0.35355339059327373f;   // sqrt(2)/4
    const float HMR = 0.14644660940672627f;   // 0.5 - RS

    #pragma unroll
    for (int c = 0; c < NCHUNK; ++c) {
        // steady state queue: [s(c):4, w(c):4, s(c+1):4] -> vmcnt(4) retires
        // s(c)+w(c), leaves s(c+1) in flight. Last phase: nothing newer.
        if (c == NCHUNK - 1) asm volatile("s_waitcnt vmcnt(0)" ::: "memory");
        else                 asm volatile("s_waitcnt vmcnt(4)" ::: "memory");
        __builtin_amdgcn_sched_barrier(0);
        __builtin_amdgcn_s_barrier();
        // prefetch next phase's weights BEFORE next stage (queue order!)
        if (c + 1 < NCHUNK) {
            const unsigned short* wr = wbl + (c + 1) * 2048;
            if ((c + 1) & 1) {
                wO0 = *(const bf16x8*)(wr);
                wO1 = *(const bf16x8*)(wr + 256);
                wO2 = *(const bf16x8*)(wr + 1024);
                wO3 = *(const bf16x8*)(wr + 1280);
            } else {
                wE0 = *(const bf16x8*)(wr);
                wE1 = *(const bf16x8*)(wr + 256);
                wE2 = *(const bf16x8*)(wr + 1024);
                wE3 = *(const bf16x8*)(wr + 1280);
            }
        }
        if (c + 2 < NCHUNK) stage(c + 2);   // WAR-safe: buf (c+2)%3 freed at barrier
        __builtin_amdgcn_sched_barrier(0);

        const bf16x8 A00 = (c & 1) ? wO0 : wE0;
        const bf16x8 A01 = (c & 1) ? wO1 : wE1;
        const bf16x8 A10 = (c & 1) ? wO2 : wE2;
        const bf16x8 A11 = (c & 1) ? wO3 : wE3;

        const float* tb = &lds[c % NBUF][0][p0 * RCOLS + pc + 3];
        #pragma unroll
        for (int kc = 0; kc < 2; ++kc) {
            bf16x8 b0, b1;
            #pragma unroll
            for (int cs = 0; cs < 2; ++cs) {
                const float* t = tb + (kc * 4 + hx * 2 + cs) * CHF;
                const float t00=t[0],   t01=t[1],   t02=t[2];
                const float t10=t[40],  t11=t[41],  t12=t[42];
                const float t20=t[80],  t21=t[81],  t22=t[82];
                const float t30=t[120], t31=t[121], t32=t[122];
                const float S0=t00+t01+t02, S1=t10+t11+t12;
                const float S2=t20+t21+t22, S3=t30+t31+t32;
                const float D0=t02-t00, D1=t12-t10, D2=t22-t20, D3=t32-t30;
                {   // pixel row p0 (staged rows 0,1,2)
                    const float F1 = RS * (S0 + S2 + S1 - t11);
                    const float B2 = RS * (D0 + D2) + 0.5f * D1;
                    const float B3 = RS * (S2 - S0) + HMR * (t21 - t01);
                    const float B4 = 0.5f * (S1 - t11 - t01 - t21);
                    const float B5 = 0.5f * (D2 - D0);
                    b0[cs*4+0] = (__bf16)t11;
                    b0[cs*4+1] = (__bf16)F1;
                    b0[cs*4+2] = (__bf16)(c1a * B2 + s1a * B3);
                    b0[cs*4+3] = (__bf16)(c2a * B4 + s2a * B5);
                }
                {   // pixel row p0+1 (staged rows 1,2,3)
                    const float F1 = RS * (S1 + S3 + S2 - t21);
                    const float B2 = RS * (D1 + D3) + 0.5f * D2;
                    const float B3 = RS * (S3 - S1) + HMR * (t31 - t11);
                    const float B4 = 0.5f * (S2 - t21 - t11 - t31);
                    const float B5 = 0.5f * (D3 - D1);
                    b1[cs*4+0] = (__bf16)t21;
                    b1[cs*4+1] = (__bf16)F1;
                    b1[cs*4+2] = (__bf16)(c1b * B2 + s1b * B3);
                    b1[cs*4+3] = (__bf16)(c2b * B4 + s2b * B5);
                }
            }
            const bf16x8 A0 = kc ? A10 : A00;
            const bf16x8 A1 = kc ? A11 : A01;
            __builtin_amdgcn_s_setprio(1);
            acc00 = __builtin_amdgcn_mfma_f32_32x32x16_bf16(A0, b0, acc00, 0, 0, 0);
            acc01 = __builtin_amdgcn_mfma_f32_32x32x16_bf16(A1, b0, acc01, 0, 0, 0);
            acc10 = __builtin_amdgcn_mfma_f32_32x32x16_bf16(A0, b1, acc10, 0, 0, 0);
            acc11 = __builtin_amdgcn_mfma_f32_32x32x16_bf16(A1, b1, acc11, 0, 0, 0);
            __builtin_amdgcn_s_setprio(0);
        }
    }

    const size_t hw = (size_t)HH * WW;
    float* op = out + (size_t)n * 64 * hw + (size_t)(h0 + p0) * WW + w0 + pc;
    #pragma unroll
    for (int r = 0; r < 16; ++r) {
        const int o = (r & 3) + 8 * (r >> 2) + 4 * hx;
        const float bo = bias[o], bo2 = bias[o + 32];
        op[(size_t)o * hw]             = acc00[r] + bo;
        op[(size_t)(o + 32) * hw]      = acc01[r] + bo2;
        op[(size_t)o * hw + WW]        = acc10[r] + bo;
        op[(size_t)(o + 32) * hw + WW] = acc11[r] + bo2;
    }
}

extern "C" void kernel_launch(void* const* d_in, const int* in_sizes, int n_in,
                              void* d_out, int out_size, void* d_ws, size_t ws_size,
                              hipStream_t stream) {
    const float* x     = (const float*)d_in[0];
    const float* theta = (const float*)d_in[1];
    const float* wt    = (const float*)d_in[2];
    const float* bias  = (const float*)d_in[3];
    float* out = (float*)d_out;
    unsigned short* wb = (unsigned short*)d_ws;   // 32 KB bf16 weights (repacked)

    wt_repack<<<64, 256, 0, stream>>>(wt, wb);

    steered_conv_mfma<<<1024, 256, 0, stream>>>(x, theta, wb, bias, out);
}